// Round 1
// baseline (157.753 us; speedup 1.0000x reference)
//
#include <hip/hip_runtime.h>
#include <math.h>

#define D_FEAT 128
#define NBINS 2048          // bin = row & 2047; bin rows are row = bin + l*2048, l<25
#define BIN_SHIFT 11
#define BIN_MASK (NBINS - 1)
#define CAPB 512            // slots per bin (avg ~391, +6 sigma) -> overflow list
#define OCAP 4096
#define P1_EPB 6400         // edges per phase-1 scatter block (25/thread)
#define GSTRIDE 32          // gcur padding: one counter per 128B cache line

typedef float    v2f __attribute__((ext_vector_type(2)));
typedef int      v2i __attribute__((ext_vector_type(2)));
typedef float    v4f __attribute__((ext_vector_type(4)));
typedef unsigned v4u __attribute__((ext_vector_type(4)));

static __device__ inline unsigned short f2bf(float f) {
    unsigned u = __float_as_uint(f);
    u += 0x7FFFu + ((u >> 16) & 1u);   // round-to-nearest-even
    return (unsigned short)(u >> 16);
}

// ===================== phase 1: fused binning + scale =======================
// Scatter role (blocks [0, nsb)): two-pass LDS binning into 2048 bins. Pass A
// counts into LDS; ONE global atomic per (block,bin) reserves a contiguous
// run (counters padded to one per cache line); pass B writes edges grouped by
// bin as packed 8B {col | local<<16, val}.
// Scale role: per-row logmap0 + bf16 row write (NT in/out).
__global__ void __launch_bounds__(256)
bin_scale_kernel(const float* __restrict__ x,
                 unsigned short* __restrict__ xt,
                 const int* __restrict__ rows,
                 const int* __restrict__ cols,
                 const float* __restrict__ vals,
                 int* __restrict__ gcur,      // NBINS*GSTRIDE ints (zeroed)
                 int* __restrict__ binned,    // v2i entries, bin*CAPB
                 int* __restrict__ ocount,
                 int4* __restrict__ oedges,
                 int n_nodes, int n_edges, int n_scatter_blocks) {
    __shared__ int cnt1[NBINS];
    __shared__ int base1[NBINS];
    __shared__ int runc[NBINS];
    if ((int)blockIdx.x < n_scatter_blocks) {
        const int tid = threadIdx.x;
        for (int b = tid; b < NBINS; b += 256) { cnt1[b] = 0; runc[b] = 0; }
        __syncthreads();
        const int e0 = blockIdx.x * P1_EPB;
        const int e1 = min(e0 + P1_EPB, n_edges);
        // pass A: count
        for (int e = e0 + tid; e < e1; e += 256) {
            int r = __builtin_nontemporal_load(rows + e);
            atomicAdd(&cnt1[r & BIN_MASK], 1);
        }
        __syncthreads();
        // reserve: one global atomic per nonempty (block,bin); padded counters
        for (int b = tid; b < NBINS; b += 256) {
            int c = cnt1[b];
            base1[b] = c ? atomicAdd(&gcur[b * GSTRIDE], c) : 0;
        }
        __syncthreads();
        // pass B: grouped writes
        for (int e = e0 + tid; e < e1; e += 256) {
            int   r = __builtin_nontemporal_load(rows + e);
            int   c = __builtin_nontemporal_load(cols + e);
            float v = __builtin_nontemporal_load(vals + e);
            int b = r & BIN_MASK;
            int slot = atomicAdd(&runc[b], 1);     // LDS
            int idx = base1[b] + slot;
            if (idx < CAPB) {
                v2i p;
                p.x = c | ((r >> BIN_SHIFT) << 16);  // col<65536, local<32
                p.y = __float_as_int(v);
                *((v2i*)(binned + 2 * ((size_t)b * CAPB + idx))) = p;
            } else {  // astronomically rare
                int o = atomicAdd(ocount, 1);
                if (o < OCAP) {
                    int4 q; q.x = r; q.y = c; q.z = __float_as_int(v); q.w = 0;
                    oedges[o] = q;
                }
            }
        }
    } else {
        const int lane = threadIdx.x & 63;
        const int wave = threadIdx.x >> 6;
        const int row = ((int)blockIdx.x - n_scatter_blocks) * 4 + wave;
        if (row >= n_nodes) return;

        v2f v = __builtin_nontemporal_load(
            (const v2f*)(x + (size_t)row * D_FEAT) + lane);
        float ss = v.x * v.x + v.y * v.y;
        #pragma unroll
        for (int off = 32; off > 0; off >>= 1)
            ss += __shfl_xor(ss, off, 64);

        float norm = sqrtf(ss);
        float nc = fmaxf(norm, 1e-15f);
        float u = fminf(nc, 1.0f - 1e-15f);
        float at = 0.5f * (log1pf(u) - log1pf(-u));
        float s = at / nc;

        unsigned packed = (unsigned)f2bf(v.x * s) |
                          ((unsigned)f2bf(v.y * s) << 16);
        __builtin_nontemporal_store(
            packed, (unsigned*)(xt + (size_t)row * D_FEAT) + lane);
    }
}

// ===================== phase 2: per-bin counting-sort + gather ==============
// One block per bin (2048 blocks -> 8 blocks/CU, 32 waves/CU). Coalesced edge
// load into LDS, counting-sort by local row (exact degrees), then
// GROUP-PER-ROW: each 16-lane group exclusively owns rows l = grp, grp+16,...
// -> no cross-group shuffle reduction, all-lane coalesced stores. Edge
// metadata read from LDS (16-lane broadcast). Rows of overflowed bins
// additionally scan the tiny oedges list inline.
__global__ void __launch_bounds__(256, 8)
gather_binned_kernel(const unsigned short* __restrict__ xt,
                     const int* __restrict__ gcur,
                     const int* __restrict__ binned,
                     const int* __restrict__ ocount,
                     const int4* __restrict__ oedges,
                     float* __restrict__ out, int n_nodes) {
    __shared__ v2i elist[CAPB];     // 4 KB
    __shared__ v2i sorted[CAPB];    // 4 KB
    __shared__ int rcnt[32], roff[32], rcur[32];

    const int bin = blockIdx.x;
    const int tid = threadIdx.x;
    const int total = gcur[bin * GSTRIDE];
    const bool over = total > CAPB;
    const int cnt = over ? CAPB : total;

    if (tid < 32) { rcnt[tid] = 0; rcur[tid] = 0; }
    __syncthreads();

    // load + count by local row
    for (int i = tid; i < cnt; i += 256) {
        v2i w = ((const v2i*)(binned + 2 * (size_t)bin * CAPB))[i];
        elist[i] = w;
        atomicAdd(&rcnt[(w.x >> 16) & 31], 1);
    }
    __syncthreads();
    // exclusive scan (<=25 rows) within a 32-lane segment
    if (tid < 32) {
        int v = rcnt[tid];
        int s = v;
        #pragma unroll
        for (int off = 1; off < 32; off <<= 1) {
            int t = __shfl_up(s, off, 32);
            if ((tid & 31) >= (unsigned)off) s += t;
        }
        roff[tid] = s - v;
    }
    __syncthreads();
    // scatter into row-sorted order
    for (int i = tid; i < cnt; i += 256) {
        v2i w = elist[i];
        int l = (w.x >> 16) & 31;
        int slot = atomicAdd(&rcur[l], 1);
        sorted[roff[l] + slot] = w;
    }
    __syncthreads();

    const int grp = tid >> 4;        // 0..15: group-per-row
    const int t   = tid & 15;        // feature lane within group
    // number of valid rows in this bin (24 or 25)
    const int nrows = (n_nodes - bin + NBINS - 1) >> BIN_SHIFT;

    for (int l = grp; l < nrows; l += 16) {
        const int row = bin + (l << BIN_SHIFT);
        const int deg = rcnt[l];
        const int off = roff[l];

        float a0 = 0, a1 = 0, a2 = 0, a3 = 0, a4 = 0, a5 = 0, a6 = 0, a7 = 0;

        for (int j = 0; j < deg; j += 2) {
            v2i s0 = sorted[off + j];
            bool h1 = (j + 1) < deg;
            v2i s1 = sorted[off + (h1 ? j + 1 : j)];
            float w0 = __int_as_float(s0.y);
            float w1 = h1 ? __int_as_float(s1.y) : 0.0f;
            int c0 = s0.x & 0xFFFF;
            int c1 = s1.x & 0xFFFF;
            v4u u0 = ((const v4u*)(xt + ((size_t)c0 << 7)))[t];
            v4u u1 = ((const v4u*)(xt + ((size_t)c1 << 7)))[t];
            a0 = fmaf(w0, __uint_as_float(u0.x << 16), a0);
            a1 = fmaf(w0, __uint_as_float(u0.x & 0xFFFF0000u), a1);
            a2 = fmaf(w0, __uint_as_float(u0.y << 16), a2);
            a3 = fmaf(w0, __uint_as_float(u0.y & 0xFFFF0000u), a3);
            a4 = fmaf(w0, __uint_as_float(u0.z << 16), a4);
            a5 = fmaf(w0, __uint_as_float(u0.z & 0xFFFF0000u), a5);
            a6 = fmaf(w0, __uint_as_float(u0.w << 16), a6);
            a7 = fmaf(w0, __uint_as_float(u0.w & 0xFFFF0000u), a7);
            a0 = fmaf(w1, __uint_as_float(u1.x << 16), a0);
            a1 = fmaf(w1, __uint_as_float(u1.x & 0xFFFF0000u), a1);
            a2 = fmaf(w1, __uint_as_float(u1.y << 16), a2);
            a3 = fmaf(w1, __uint_as_float(u1.y & 0xFFFF0000u), a3);
            a4 = fmaf(w1, __uint_as_float(u1.z << 16), a4);
            a5 = fmaf(w1, __uint_as_float(u1.z & 0xFFFF0000u), a5);
            a6 = fmaf(w1, __uint_as_float(u1.w << 16), a6);
            a7 = fmaf(w1, __uint_as_float(u1.w & 0xFFFF0000u), a7);
        }

        if (over) {  // exact rescue of edges that missed the bin region
            int n = *ocount;
            n = n < OCAP ? n : OCAP;
            for (int j = 0; j < n; ++j) {
                int4 q = oedges[j];
                if (q.x == row) {   // group owns this row exclusively
                    float w = __int_as_float(q.z);
                    v4u u = ((const v4u*)(xt + ((size_t)q.y << 7)))[t];
                    a0 = fmaf(w, __uint_as_float(u.x << 16), a0);
                    a1 = fmaf(w, __uint_as_float(u.x & 0xFFFF0000u), a1);
                    a2 = fmaf(w, __uint_as_float(u.y << 16), a2);
                    a3 = fmaf(w, __uint_as_float(u.y & 0xFFFF0000u), a3);
                    a4 = fmaf(w, __uint_as_float(u.z << 16), a4);
                    a5 = fmaf(w, __uint_as_float(u.z & 0xFFFF0000u), a5);
                    a6 = fmaf(w, __uint_as_float(u.w << 16), a6);
                    a7 = fmaf(w, __uint_as_float(u.w & 0xFFFF0000u), a7);
                }
            }
        }

        // all 16 lanes store: 16 * 32B = 512B coalesced per row
        v4f* op = (v4f*)(out + ((size_t)row << 7) + t * 8);
        v4f o0; o0.x = a0; o0.y = a1; o0.z = a2; o0.w = a3;
        v4f o1; o1.x = a4; o1.y = a5; o1.z = a6; o1.w = a7;
        __builtin_nontemporal_store(o0, op);
        __builtin_nontemporal_store(o1, op + 1);
    }
}

// ===================== fallback (tiny ws; never expected) ===================
__global__ void fallback_kernel(const float* __restrict__ x,
                                const int* __restrict__ rows,
                                const int* __restrict__ cols,
                                const float* __restrict__ vals,
                                float* __restrict__ out, int n_edges) {
    int gid = blockIdx.x * blockDim.x + threadIdx.x;
    int e = gid >> 5, t = gid & 31;
    if (e >= n_edges) return;
    int c = cols[e];
    const float* xr = x + (size_t)c * D_FEAT;
    float ss = 0.0f;
    for (int i = 0; i < D_FEAT; ++i) ss += xr[i] * xr[i];
    float nc = fmaxf(sqrtf(ss), 1e-15f);
    float u = fminf(nc, 1.0f - 1e-15f);
    float w = vals[e] * (0.5f * (log1pf(u) - log1pf(-u))) / nc;
    const float4* xc = (const float4*)xr;
    float4 xv = xc[t];
    float* o = out + (size_t)rows[e] * D_FEAT + t * 4;
    atomicAdd(o + 0, w * xv.x);
    atomicAdd(o + 1, w * xv.y);
    atomicAdd(o + 2, w * xv.z);
    atomicAdd(o + 3, w * xv.w);
}

// ============================================================================

extern "C" void kernel_launch(void* const* d_in, const int* in_sizes, int n_in,
                              void* d_out, int out_size, void* d_ws, size_t ws_size,
                              hipStream_t stream) {
    const float* x    = (const float*)d_in[0];
    const int*   rows = (const int*)d_in[1];
    const int*   cols = (const int*)d_in[2];
    const float* vals = (const float*)d_in[3];
    float* out = (float*)d_out;

    const int n_nodes = in_sizes[0] / D_FEAT;  // 50000
    const int n_edges = in_sizes[1];           // 800000

    char* wsb = (char*)d_ws;
    const int n_scatter_blocks = (n_edges + P1_EPB - 1) / P1_EPB;  // 125
    const int n_scale_blocks   = (n_nodes + 3) / 4;                // 12500

    size_t xt_bytes    = (size_t)n_nodes * D_FEAT * 2;             // 12.8 MB
    size_t gcur_off    = xt_bytes;
    size_t gcur_bytes  = (size_t)NBINS * GSTRIDE * 4;              // 256 KB
    size_t ocount_off  = gcur_off + gcur_bytes;
    size_t oedges_off  = (ocount_off + 4 + 255) & ~(size_t)255;
    size_t binned_off  = (oedges_off + (size_t)OCAP * 16 + 511) & ~(size_t)511;
    size_t need        = binned_off + (size_t)NBINS * CAPB * 8;    // ~21.5 MB

    if (ws_size >= need) {
        unsigned short* xt = (unsigned short*)wsb;
        int*  gcur    = (int*)(wsb + gcur_off);
        int*  ocount  = (int*)(wsb + ocount_off);
        int4* oedges  = (int4*)(wsb + oedges_off);
        int*  binned  = (int*)(wsb + binned_off);

        // zero bin cursors + ocount in one memset
        hipMemsetAsync(gcur, 0, ocount_off + 4 - gcur_off, stream);
        bin_scale_kernel<<<n_scatter_blocks + n_scale_blocks, 256, 0, stream>>>(
            x, xt, rows, cols, vals, gcur, binned, ocount, oedges,
            n_nodes, n_edges, n_scatter_blocks);
        gather_binned_kernel<<<NBINS, 256, 0, stream>>>(
            xt, gcur, binned, ocount, oedges, out, n_nodes);
    } else {
        hipMemsetAsync(out, 0, (size_t)out_size * sizeof(float), stream);
        long long total = (long long)n_edges * 32;
        fallback_kernel<<<(int)((total + 255) / 256), 256, 0, stream>>>(
            x, rows, cols, vals, out, n_edges);
    }
}

// Round 2
// 152.918 us; speedup vs baseline: 1.0316x; 1.0316x over previous
//
#include <hip/hip_runtime.h>
#include <math.h>

#define D_FEAT 128
#define NBINS 1024          // bin = row & 1023; bin rows are row = bin + l*1024, l<49
#define BIN_MASK (NBINS - 1)
#define CAPB 1024           // slots per bin (avg 781, +8.7 sigma) -> overflow list
#define OCAP 4096
#define P1_EPB 6400         // edges per phase-1 scatter block (25/thread)

typedef float    v2f __attribute__((ext_vector_type(2)));
typedef int      v2i __attribute__((ext_vector_type(2)));
typedef float    v4f __attribute__((ext_vector_type(4)));
typedef unsigned v4u __attribute__((ext_vector_type(4)));

static __device__ inline unsigned short f2bf(float f) {
    unsigned u = __float_as_uint(f);
    u += 0x7FFFu + ((u >> 16) & 1u);   // round-to-nearest-even
    return (unsigned short)(u >> 16);
}

// ===================== phase 1: fused binning + scale =======================
// (identical to the 145us R0 version — NBINS=1024, 12KB LDS so the scale role
// keeps 13 blocks/CU; 125x1024 reserve atomics)
__global__ void __launch_bounds__(256)
bin_scale_kernel(const float* __restrict__ x,
                 unsigned short* __restrict__ xt,
                 const int* __restrict__ rows,
                 const int* __restrict__ cols,
                 const float* __restrict__ vals,
                 int* __restrict__ gcur,      // NBINS ints (zeroed)
                 int* __restrict__ binned,    // v2i entries, bin*CAPB
                 int* __restrict__ ocount,
                 int4* __restrict__ oedges,
                 int n_nodes, int n_edges, int n_scatter_blocks) {
    __shared__ int cnt1[NBINS];
    __shared__ int base1[NBINS];
    __shared__ int runc[NBINS];
    if ((int)blockIdx.x < n_scatter_blocks) {
        const int tid = threadIdx.x;
        for (int b = tid; b < NBINS; b += 256) { cnt1[b] = 0; runc[b] = 0; }
        __syncthreads();
        const int e0 = blockIdx.x * P1_EPB;
        const int e1 = min(e0 + P1_EPB, n_edges);
        // pass A: count
        for (int e = e0 + tid; e < e1; e += 256) {
            int r = __builtin_nontemporal_load(rows + e);
            atomicAdd(&cnt1[r & BIN_MASK], 1);
        }
        __syncthreads();
        // reserve: one global atomic per nonempty (block,bin)
        for (int b = tid; b < NBINS; b += 256) {
            int c = cnt1[b];
            base1[b] = c ? atomicAdd(&gcur[b], c) : 0;
        }
        __syncthreads();
        // pass B: grouped writes
        for (int e = e0 + tid; e < e1; e += 256) {
            int   r = __builtin_nontemporal_load(rows + e);
            int   c = __builtin_nontemporal_load(cols + e);
            float v = __builtin_nontemporal_load(vals + e);
            int b = r & BIN_MASK;
            int slot = atomicAdd(&runc[b], 1);     // LDS
            int idx = base1[b] + slot;
            if (idx < CAPB) {
                v2i p;
                p.x = c | ((r >> 10) << 16);       // col<65536, local<64
                p.y = __float_as_int(v);
                *((v2i*)(binned + 2 * ((size_t)b * CAPB + idx))) = p;
            } else {  // astronomically rare
                int o = atomicAdd(ocount, 1);
                if (o < OCAP) {
                    int4 q; q.x = r; q.y = c; q.z = __float_as_int(v); q.w = 0;
                    oedges[o] = q;
                }
            }
        }
    } else {
        const int lane = threadIdx.x & 63;
        const int wave = threadIdx.x >> 6;
        const int row = ((int)blockIdx.x - n_scatter_blocks) * 4 + wave;
        if (row >= n_nodes) return;

        v2f v = __builtin_nontemporal_load(
            (const v2f*)(x + (size_t)row * D_FEAT) + lane);
        float ss = v.x * v.x + v.y * v.y;
        #pragma unroll
        for (int off = 32; off > 0; off >>= 1)
            ss += __shfl_xor(ss, off, 64);

        float norm = sqrtf(ss);
        float nc = fmaxf(norm, 1e-15f);
        float u = fminf(nc, 1.0f - 1e-15f);
        float at = 0.5f * (log1pf(u) - log1pf(-u));
        float s = at / nc;

        unsigned packed = (unsigned)f2bf(v.x * s) |
                          ((unsigned)f2bf(v.y * s) << 16);
        __builtin_nontemporal_store(
            packed, (unsigned*)(xt + (size_t)row * D_FEAT) + lane);
    }
}

// ===================== phase 2: per-bin counting-sort + gather ==============
// One block of 512 threads per bin: 1024 blocks = exactly 4 blocks/CU =
// 32 waves/CU (launch_bounds forces VGPR<=64). 32 groups of 16 lanes, each
// group exclusively owns rows l = grp, grp+32 (no cross-group reduction,
// all-lane stores). Inner loop is UNROLL-4: 4 independent 16B xt loads in
// flight per group (2x the previous MLP — the kernel is latency-bound on
// these random fetches). sorted[] is zero-padded so only the edge weight
// needs range-masking, never the address.
__global__ void __launch_bounds__(512, 8)
gather_binned_kernel(const unsigned short* __restrict__ xt,
                     const int* __restrict__ gcur,
                     const int* __restrict__ binned,
                     const int* __restrict__ ocount,
                     const int4* __restrict__ oedges,
                     float* __restrict__ out, int n_nodes) {
    __shared__ v2i elist[CAPB];        // 8 KB
    __shared__ v2i sorted[CAPB + 4];   // 8 KB + pad
    __shared__ int rcnt[64], roff[64], rcur[64];

    const int bin = blockIdx.x;
    const int tid = threadIdx.x;
    const int total = gcur[bin];
    const bool over = total > CAPB;
    const int cnt = over ? CAPB : total;

    if (tid < 64) { rcnt[tid] = 0; rcur[tid] = 0; }
    __syncthreads();

    // load + count by local row
    for (int i = tid; i < cnt; i += 512) {
        v2i w = ((const v2i*)(binned + 2 * (size_t)bin * CAPB))[i];
        elist[i] = w;
        atomicAdd(&rcnt[(w.x >> 16) & 63], 1);
    }
    __syncthreads();
    // exclusive scan (49 rows) by wave 0
    if (tid < 64) {
        int v = rcnt[tid];
        int s = v;
        #pragma unroll
        for (int off = 1; off < 64; off <<= 1) {
            int t = __shfl_up(s, off, 64);
            if (tid >= (unsigned)off) s += t;
        }
        roff[tid] = s - v;
    }
    __syncthreads();
    // scatter into row-sorted order
    for (int i = tid; i < cnt; i += 512) {
        v2i w = elist[i];
        int l = (w.x >> 16) & 63;
        int slot = atomicAdd(&rcur[l], 1);
        sorted[roff[l] + slot] = w;
    }
    // zero-pad tail so unroll-4 reads past the last row are {col=0, w=0}
    if (tid < 4) { v2i z; z.x = 0; z.y = 0; sorted[cnt + tid] = z; }
    __syncthreads();

    const int grp = tid >> 4;        // 0..31: group-per-row
    const int t   = tid & 15;        // feature lane within group
    const int nrows = (n_nodes - bin + NBINS - 1) >> 10;   // 48 or 49

    for (int l = grp; l < nrows; l += 32) {
        const int row = bin + (l << 10);
        const int deg = rcnt[l];
        const int off = roff[l];

        float a0 = 0, a1 = 0, a2 = 0, a3 = 0, a4 = 0, a5 = 0, a6 = 0, a7 = 0;

        for (int j = 0; j < deg; j += 4) {
            // 4 unconditional LDS reads (pad/next-row entries are safe cols)
            v2i s0 = sorted[off + j];
            v2i s1 = sorted[off + j + 1];
            v2i s2 = sorted[off + j + 2];
            v2i s3 = sorted[off + j + 3];
            float w0 = __int_as_float(s0.y);
            float w1 = (j + 1 < deg) ? __int_as_float(s1.y) : 0.0f;
            float w2 = (j + 2 < deg) ? __int_as_float(s2.y) : 0.0f;
            float w3 = (j + 3 < deg) ? __int_as_float(s3.y) : 0.0f;
            int c0 = s0.x & 0xFFFF;
            int c1 = s1.x & 0xFFFF;
            int c2 = s2.x & 0xFFFF;
            int c3 = s3.x & 0xFFFF;
            // 4 independent 16B loads in flight
            v4u u0 = ((const v4u*)(xt + ((size_t)c0 << 7)))[t];
            v4u u1 = ((const v4u*)(xt + ((size_t)c1 << 7)))[t];
            v4u u2 = ((const v4u*)(xt + ((size_t)c2 << 7)))[t];
            v4u u3 = ((const v4u*)(xt + ((size_t)c3 << 7)))[t];
            a0 = fmaf(w0, __uint_as_float(u0.x << 16), a0);
            a1 = fmaf(w0, __uint_as_float(u0.x & 0xFFFF0000u), a1);
            a2 = fmaf(w0, __uint_as_float(u0.y << 16), a2);
            a3 = fmaf(w0, __uint_as_float(u0.y & 0xFFFF0000u), a3);
            a4 = fmaf(w0, __uint_as_float(u0.z << 16), a4);
            a5 = fmaf(w0, __uint_as_float(u0.z & 0xFFFF0000u), a5);
            a6 = fmaf(w0, __uint_as_float(u0.w << 16), a6);
            a7 = fmaf(w0, __uint_as_float(u0.w & 0xFFFF0000u), a7);
            a0 = fmaf(w1, __uint_as_float(u1.x << 16), a0);
            a1 = fmaf(w1, __uint_as_float(u1.x & 0xFFFF0000u), a1);
            a2 = fmaf(w1, __uint_as_float(u1.y << 16), a2);
            a3 = fmaf(w1, __uint_as_float(u1.y & 0xFFFF0000u), a3);
            a4 = fmaf(w1, __uint_as_float(u1.z << 16), a4);
            a5 = fmaf(w1, __uint_as_float(u1.z & 0xFFFF0000u), a5);
            a6 = fmaf(w1, __uint_as_float(u1.w << 16), a6);
            a7 = fmaf(w1, __uint_as_float(u1.w & 0xFFFF0000u), a7);
            a0 = fmaf(w2, __uint_as_float(u2.x << 16), a0);
            a1 = fmaf(w2, __uint_as_float(u2.x & 0xFFFF0000u), a1);
            a2 = fmaf(w2, __uint_as_float(u2.y << 16), a2);
            a3 = fmaf(w2, __uint_as_float(u2.y & 0xFFFF0000u), a3);
            a4 = fmaf(w2, __uint_as_float(u2.z << 16), a4);
            a5 = fmaf(w2, __uint_as_float(u2.z & 0xFFFF0000u), a5);
            a6 = fmaf(w2, __uint_as_float(u2.w << 16), a6);
            a7 = fmaf(w2, __uint_as_float(u2.w & 0xFFFF0000u), a7);
            a0 = fmaf(w3, __uint_as_float(u3.x << 16), a0);
            a1 = fmaf(w3, __uint_as_float(u3.x & 0xFFFF0000u), a1);
            a2 = fmaf(w3, __uint_as_float(u3.y << 16), a2);
            a3 = fmaf(w3, __uint_as_float(u3.y & 0xFFFF0000u), a3);
            a4 = fmaf(w3, __uint_as_float(u3.z << 16), a4);
            a5 = fmaf(w3, __uint_as_float(u3.z & 0xFFFF0000u), a5);
            a6 = fmaf(w3, __uint_as_float(u3.w << 16), a6);
            a7 = fmaf(w3, __uint_as_float(u3.w & 0xFFFF0000u), a7);
        }

        if (over) {  // exact rescue of edges that missed the bin region
            int n = *ocount;
            n = n < OCAP ? n : OCAP;
            for (int j = 0; j < n; ++j) {
                int4 q = oedges[j];
                if (q.x == row) {   // group owns this row exclusively
                    float w = __int_as_float(q.z);
                    v4u u = ((const v4u*)(xt + ((size_t)q.y << 7)))[t];
                    a0 = fmaf(w, __uint_as_float(u.x << 16), a0);
                    a1 = fmaf(w, __uint_as_float(u.x & 0xFFFF0000u), a1);
                    a2 = fmaf(w, __uint_as_float(u.y << 16), a2);
                    a3 = fmaf(w, __uint_as_float(u.y & 0xFFFF0000u), a3);
                    a4 = fmaf(w, __uint_as_float(u.z << 16), a4);
                    a5 = fmaf(w, __uint_as_float(u.z & 0xFFFF0000u), a5);
                    a6 = fmaf(w, __uint_as_float(u.w << 16), a6);
                    a7 = fmaf(w, __uint_as_float(u.w & 0xFFFF0000u), a7);
                }
            }
        }

        // all 16 lanes store: 16 * 32B = 512B coalesced per row
        v4f* op = (v4f*)(out + ((size_t)row << 7) + t * 8);
        v4f o0; o0.x = a0; o0.y = a1; o0.z = a2; o0.w = a3;
        v4f o1; o1.x = a4; o1.y = a5; o1.z = a6; o1.w = a7;
        __builtin_nontemporal_store(o0, op);
        __builtin_nontemporal_store(o1, op + 1);
    }
}

// ===================== fallback (tiny ws; never expected) ===================
__global__ void fallback_kernel(const float* __restrict__ x,
                                const int* __restrict__ rows,
                                const int* __restrict__ cols,
                                const float* __restrict__ vals,
                                float* __restrict__ out, int n_edges) {
    int gid = blockIdx.x * blockDim.x + threadIdx.x;
    int e = gid >> 5, t = gid & 31;
    if (e >= n_edges) return;
    int c = cols[e];
    const float* xr = x + (size_t)c * D_FEAT;
    float ss = 0.0f;
    for (int i = 0; i < D_FEAT; ++i) ss += xr[i] * xr[i];
    float nc = fmaxf(sqrtf(ss), 1e-15f);
    float u = fminf(nc, 1.0f - 1e-15f);
    float w = vals[e] * (0.5f * (log1pf(u) - log1pf(-u))) / nc;
    const float4* xc = (const float4*)xr;
    float4 xv = xc[t];
    float* o = out + (size_t)rows[e] * D_FEAT + t * 4;
    atomicAdd(o + 0, w * xv.x);
    atomicAdd(o + 1, w * xv.y);
    atomicAdd(o + 2, w * xv.z);
    atomicAdd(o + 3, w * xv.w);
}

// ============================================================================

extern "C" void kernel_launch(void* const* d_in, const int* in_sizes, int n_in,
                              void* d_out, int out_size, void* d_ws, size_t ws_size,
                              hipStream_t stream) {
    const float* x    = (const float*)d_in[0];
    const int*   rows = (const int*)d_in[1];
    const int*   cols = (const int*)d_in[2];
    const float* vals = (const float*)d_in[3];
    float* out = (float*)d_out;

    const int n_nodes = in_sizes[0] / D_FEAT;  // 50000
    const int n_edges = in_sizes[1];           // 800000

    char* wsb = (char*)d_ws;
    const int n_scatter_blocks = (n_edges + P1_EPB - 1) / P1_EPB;  // 125
    const int n_scale_blocks   = (n_nodes + 3) / 4;                // 12500

    size_t xt_bytes    = (size_t)n_nodes * D_FEAT * 2;             // 12.8 MB
    size_t gcur_off    = xt_bytes;
    size_t ocount_off  = gcur_off + (size_t)NBINS * 4;
    size_t oedges_off  = (ocount_off + 4 + 255) & ~(size_t)255;
    size_t binned_off  = (oedges_off + (size_t)OCAP * 16 + 511) & ~(size_t)511;
    size_t need        = binned_off + (size_t)NBINS * CAPB * 8;    // ~21.3 MB

    if (ws_size >= need) {
        unsigned short* xt = (unsigned short*)wsb;
        int*  gcur    = (int*)(wsb + gcur_off);
        int*  ocount  = (int*)(wsb + ocount_off);
        int4* oedges  = (int4*)(wsb + oedges_off);
        int*  binned  = (int*)(wsb + binned_off);

        // zero bin cursors + ocount in one memset
        hipMemsetAsync(gcur, 0, ocount_off + 4 - gcur_off, stream);
        bin_scale_kernel<<<n_scatter_blocks + n_scale_blocks, 256, 0, stream>>>(
            x, xt, rows, cols, vals, gcur, binned, ocount, oedges,
            n_nodes, n_edges, n_scatter_blocks);
        gather_binned_kernel<<<NBINS, 512, 0, stream>>>(
            xt, gcur, binned, ocount, oedges, out, n_nodes);
    } else {
        hipMemsetAsync(out, 0, (size_t)out_size * sizeof(float), stream);
        long long total = (long long)n_edges * 32;
        fallback_kernel<<<(int)((total + 255) / 256), 256, 0, stream>>>(
            x, rows, cols, vals, out, n_edges);
    }
}

// Round 4
// 140.323 us; speedup vs baseline: 1.1242x; 1.0898x over previous
//
#include <hip/hip_runtime.h>
#include <math.h>

#define D_FEAT 128
#define NBINS 1024          // bin = row & 1023; bin rows are row = bin + l*1024, l<49
#define BIN_MASK (NBINS - 1)
#define CAPB 1024           // slots per bin (avg 781, +8.7 sigma) -> overflow list
#define OCAP 4096
#define P1_EPB 6400         // edges per phase-1 scatter block (25/thread)

typedef float    v2f __attribute__((ext_vector_type(2)));
typedef int      v2i __attribute__((ext_vector_type(2)));
typedef float    v4f __attribute__((ext_vector_type(4)));
typedef int      v4i __attribute__((ext_vector_type(4)));
typedef unsigned v4u __attribute__((ext_vector_type(4)));

static __device__ inline unsigned short f2bf(float f) {
    unsigned u = __float_as_uint(f);
    u += 0x7FFFu + ((u >> 16) & 1u);   // round-to-nearest-even
    return (unsigned short)(u >> 16);
}

// ===================== phase 1: fused binning + scale =======================
// Scatter role (blocks [0, nsb)): two-pass LDS binning. Edge loads are
// BATCHED 4-WIDE (ext-vector v4i/v4f — __builtin_nontemporal_load rejects
// HIP_vector_type) — the R0-R2 version issued one dependent scalar NT load
// per edge per pass (25 x ~900cy = the 125-block tail that capped this
// kernel at ~43us). Reserve: one global atomic per (block,bin).
// Scale role: per-row logmap0 + bf16 row write (unchanged, BW-capable).
__global__ void __launch_bounds__(256)
bin_scale_kernel(const float* __restrict__ x,
                 unsigned short* __restrict__ xt,
                 const int* __restrict__ rows,
                 const int* __restrict__ cols,
                 const float* __restrict__ vals,
                 int* __restrict__ gcur,      // NBINS ints (zeroed)
                 int* __restrict__ binned,    // v2i entries, bin*CAPB
                 int* __restrict__ ocount,
                 int4* __restrict__ oedges,
                 int n_nodes, int n_edges, int n_scatter_blocks) {
    __shared__ int cnt1[NBINS];
    __shared__ int base1[NBINS];
    __shared__ int runc[NBINS];
    if ((int)blockIdx.x < n_scatter_blocks) {
        const int tid = threadIdx.x;
        for (int b = tid; b < NBINS; b += 256) { cnt1[b] = 0; runc[b] = 0; }
        __syncthreads();
        const int e0 = blockIdx.x * P1_EPB;
        const int e1 = min(e0 + P1_EPB, n_edges);
        const int nfull = (e1 - e0) & ~3;      // 4-aligned prefix
        // pass A: count (4 edges per v4i load, pipelined)
        for (int e = e0 + (tid << 2); e + 3 < e1; e += 1024) {
            v4i r4 = __builtin_nontemporal_load((const v4i*)(rows + e));
            atomicAdd(&cnt1[r4[0] & BIN_MASK], 1);
            atomicAdd(&cnt1[r4[1] & BIN_MASK], 1);
            atomicAdd(&cnt1[r4[2] & BIN_MASK], 1);
            atomicAdd(&cnt1[r4[3] & BIN_MASK], 1);
        }
        for (int e = e0 + nfull + tid; e < e1; e += 256) {   // ragged tail
            int r = __builtin_nontemporal_load(rows + e);
            atomicAdd(&cnt1[r & BIN_MASK], 1);
        }
        __syncthreads();
        // reserve: one global atomic per nonempty (block,bin)
        for (int b = tid; b < NBINS; b += 256) {
            int c = cnt1[b];
            base1[b] = c ? atomicAdd(&gcur[b], c) : 0;
        }
        __syncthreads();
        // pass B: grouped writes (4 edges per iteration, 3 vector loads)
        for (int e = e0 + (tid << 2); e + 3 < e1; e += 1024) {
            v4i r4 = __builtin_nontemporal_load((const v4i*)(rows + e));
            v4i c4 = __builtin_nontemporal_load((const v4i*)(cols + e));
            v4f v4 = __builtin_nontemporal_load((const v4f*)(vals + e));
            #pragma unroll
            for (int k = 0; k < 4; ++k) {
                int   r = r4[k];
                int   c = c4[k];
                float v = v4[k];
                int b = r & BIN_MASK;
                int slot = atomicAdd(&runc[b], 1);     // LDS
                int idx = base1[b] + slot;
                if (idx < CAPB) {
                    v2i p;
                    p.x = c | ((r >> 10) << 16);       // col<65536, local<64
                    p.y = __float_as_int(v);
                    *((v2i*)(binned + 2 * ((size_t)b * CAPB + idx))) = p;
                } else {  // astronomically rare
                    int o = atomicAdd(ocount, 1);
                    if (o < OCAP) {
                        int4 q; q.x = r; q.y = c; q.z = __float_as_int(v); q.w = 0;
                        oedges[o] = q;
                    }
                }
            }
        }
        for (int e = e0 + nfull + tid; e < e1; e += 256) {   // ragged tail
            int   r = __builtin_nontemporal_load(rows + e);
            int   c = __builtin_nontemporal_load(cols + e);
            float v = __builtin_nontemporal_load(vals + e);
            int b = r & BIN_MASK;
            int slot = atomicAdd(&runc[b], 1);
            int idx = base1[b] + slot;
            if (idx < CAPB) {
                v2i p;
                p.x = c | ((r >> 10) << 16);
                p.y = __float_as_int(v);
                *((v2i*)(binned + 2 * ((size_t)b * CAPB + idx))) = p;
            } else {
                int o = atomicAdd(ocount, 1);
                if (o < OCAP) {
                    int4 q; q.x = r; q.y = c; q.z = __float_as_int(v); q.w = 0;
                    oedges[o] = q;
                }
            }
        }
    } else {
        const int lane = threadIdx.x & 63;
        const int wave = threadIdx.x >> 6;
        const int row = ((int)blockIdx.x - n_scatter_blocks) * 4 + wave;
        if (row >= n_nodes) return;

        v2f v = __builtin_nontemporal_load(
            (const v2f*)(x + (size_t)row * D_FEAT) + lane);
        float ss = v.x * v.x + v.y * v.y;
        #pragma unroll
        for (int off = 32; off > 0; off >>= 1)
            ss += __shfl_xor(ss, off, 64);

        float norm = sqrtf(ss);
        float nc = fmaxf(norm, 1e-15f);
        float u = fminf(nc, 1.0f - 1e-15f);
        float at = 0.5f * (log1pf(u) - log1pf(-u));
        float s = at / nc;

        unsigned packed = (unsigned)f2bf(v.x * s) |
                          ((unsigned)f2bf(v.y * s) << 16);
        __builtin_nontemporal_store(
            packed, (unsigned*)(xt + (size_t)row * D_FEAT) + lane);
    }
}

// ===================== phase 2: per-bin counting-sort + gather ==============
// One block of 256 threads per bin; __launch_bounds__(256,4) -> VGPR<=128
// (the R2 512-thread/(512,8) variant forced VGPR<=64 and almost certainly
// spilled the unroll-4 body). 16 groups of 16 lanes, each group exclusively
// owns rows l = grp, grp+16, ... (no cross-group reduction, all-lane
// stores). Inner loop UNROLL-4: 4 independent 16B xt loads in flight per
// group. sorted[] zero-padded so only weights need masking, never addresses.
__global__ void __launch_bounds__(256, 4)
gather_binned_kernel(const unsigned short* __restrict__ xt,
                     const int* __restrict__ gcur,
                     const int* __restrict__ binned,
                     const int* __restrict__ ocount,
                     const int4* __restrict__ oedges,
                     float* __restrict__ out, int n_nodes) {
    __shared__ v2i elist[CAPB];        // 8 KB
    __shared__ v2i sorted[CAPB + 4];   // 8 KB + pad
    __shared__ int rcnt[64], roff[64], rcur[64];

    const int bin = blockIdx.x;
    const int tid = threadIdx.x;
    const int total = gcur[bin];
    const bool over = total > CAPB;
    const int cnt = over ? CAPB : total;

    if (tid < 64) { rcnt[tid] = 0; rcur[tid] = 0; }
    __syncthreads();

    // load + count by local row
    for (int i = tid; i < cnt; i += 256) {
        v2i w = ((const v2i*)(binned + 2 * (size_t)bin * CAPB))[i];
        elist[i] = w;
        atomicAdd(&rcnt[(w.x >> 16) & 63], 1);
    }
    __syncthreads();
    // exclusive scan (49 rows) by wave 0
    if (tid < 64) {
        int v = rcnt[tid];
        int s = v;
        #pragma unroll
        for (int off = 1; off < 64; off <<= 1) {
            int t = __shfl_up(s, off, 64);
            if (tid >= (unsigned)off) s += t;
        }
        roff[tid] = s - v;
    }
    __syncthreads();
    // scatter into row-sorted order
    for (int i = tid; i < cnt; i += 256) {
        v2i w = elist[i];
        int l = (w.x >> 16) & 63;
        int slot = atomicAdd(&rcur[l], 1);
        sorted[roff[l] + slot] = w;
    }
    // zero-pad tail so unroll-4 reads past the last row are {col=0, w=0}
    if (tid < 4) { v2i z; z.x = 0; z.y = 0; sorted[cnt + tid] = z; }
    __syncthreads();

    const int grp = tid >> 4;        // 0..15: group-per-row
    const int t   = tid & 15;        // feature lane within group
    const int nrows = (n_nodes - bin + NBINS - 1) >> 10;   // 48 or 49

    for (int l = grp; l < nrows; l += 16) {
        const int row = bin + (l << 10);
        const int deg = rcnt[l];
        const int off = roff[l];

        float a0 = 0, a1 = 0, a2 = 0, a3 = 0, a4 = 0, a5 = 0, a6 = 0, a7 = 0;

        for (int j = 0; j < deg; j += 4) {
            // 4 unconditional LDS reads (pad/next-row entries are safe cols)
            v2i s0 = sorted[off + j];
            v2i s1 = sorted[off + j + 1];
            v2i s2 = sorted[off + j + 2];
            v2i s3 = sorted[off + j + 3];
            float w0 = __int_as_float(s0.y);
            float w1 = (j + 1 < deg) ? __int_as_float(s1.y) : 0.0f;
            float w2 = (j + 2 < deg) ? __int_as_float(s2.y) : 0.0f;
            float w3 = (j + 3 < deg) ? __int_as_float(s3.y) : 0.0f;
            int c0 = s0.x & 0xFFFF;
            int c1 = s1.x & 0xFFFF;
            int c2 = s2.x & 0xFFFF;
            int c3 = s3.x & 0xFFFF;
            // 4 independent 16B loads in flight
            v4u u0 = ((const v4u*)(xt + ((size_t)c0 << 7)))[t];
            v4u u1 = ((const v4u*)(xt + ((size_t)c1 << 7)))[t];
            v4u u2 = ((const v4u*)(xt + ((size_t)c2 << 7)))[t];
            v4u u3 = ((const v4u*)(xt + ((size_t)c3 << 7)))[t];
            a0 = fmaf(w0, __uint_as_float(u0.x << 16), a0);
            a1 = fmaf(w0, __uint_as_float(u0.x & 0xFFFF0000u), a1);
            a2 = fmaf(w0, __uint_as_float(u0.y << 16), a2);
            a3 = fmaf(w0, __uint_as_float(u0.y & 0xFFFF0000u), a3);
            a4 = fmaf(w0, __uint_as_float(u0.z << 16), a4);
            a5 = fmaf(w0, __uint_as_float(u0.z & 0xFFFF0000u), a5);
            a6 = fmaf(w0, __uint_as_float(u0.w << 16), a6);
            a7 = fmaf(w0, __uint_as_float(u0.w & 0xFFFF0000u), a7);
            a0 = fmaf(w1, __uint_as_float(u1.x << 16), a0);
            a1 = fmaf(w1, __uint_as_float(u1.x & 0xFFFF0000u), a1);
            a2 = fmaf(w1, __uint_as_float(u1.y << 16), a2);
            a3 = fmaf(w1, __uint_as_float(u1.y & 0xFFFF0000u), a3);
            a4 = fmaf(w1, __uint_as_float(u1.z << 16), a4);
            a5 = fmaf(w1, __uint_as_float(u1.z & 0xFFFF0000u), a5);
            a6 = fmaf(w1, __uint_as_float(u1.w << 16), a6);
            a7 = fmaf(w1, __uint_as_float(u1.w & 0xFFFF0000u), a7);
            a0 = fmaf(w2, __uint_as_float(u2.x << 16), a0);
            a1 = fmaf(w2, __uint_as_float(u2.x & 0xFFFF0000u), a1);
            a2 = fmaf(w2, __uint_as_float(u2.y << 16), a2);
            a3 = fmaf(w2, __uint_as_float(u2.y & 0xFFFF0000u), a3);
            a4 = fmaf(w2, __uint_as_float(u2.z << 16), a4);
            a5 = fmaf(w2, __uint_as_float(u2.z & 0xFFFF0000u), a5);
            a6 = fmaf(w2, __uint_as_float(u2.w << 16), a6);
            a7 = fmaf(w2, __uint_as_float(u2.w & 0xFFFF0000u), a7);
            a0 = fmaf(w3, __uint_as_float(u3.x << 16), a0);
            a1 = fmaf(w3, __uint_as_float(u3.x & 0xFFFF0000u), a1);
            a2 = fmaf(w3, __uint_as_float(u3.y << 16), a2);
            a3 = fmaf(w3, __uint_as_float(u3.y & 0xFFFF0000u), a3);
            a4 = fmaf(w3, __uint_as_float(u3.z << 16), a4);
            a5 = fmaf(w3, __uint_as_float(u3.z & 0xFFFF0000u), a5);
            a6 = fmaf(w3, __uint_as_float(u3.w << 16), a6);
            a7 = fmaf(w3, __uint_as_float(u3.w & 0xFFFF0000u), a7);
        }

        if (over) {  // exact rescue of edges that missed the bin region
            int n = *ocount;
            n = n < OCAP ? n : OCAP;
            for (int j = 0; j < n; ++j) {
                int4 q = oedges[j];
                if (q.x == row) {   // group owns this row exclusively
                    float w = __int_as_float(q.z);
                    v4u u = ((const v4u*)(xt + ((size_t)q.y << 7)))[t];
                    a0 = fmaf(w, __uint_as_float(u.x << 16), a0);
                    a1 = fmaf(w, __uint_as_float(u.x & 0xFFFF0000u), a1);
                    a2 = fmaf(w, __uint_as_float(u.y << 16), a2);
                    a3 = fmaf(w, __uint_as_float(u.y & 0xFFFF0000u), a3);
                    a4 = fmaf(w, __uint_as_float(u.z << 16), a4);
                    a5 = fmaf(w, __uint_as_float(u.z & 0xFFFF0000u), a5);
                    a6 = fmaf(w, __uint_as_float(u.w << 16), a6);
                    a7 = fmaf(w, __uint_as_float(u.w & 0xFFFF0000u), a7);
                }
            }
        }

        // all 16 lanes store: 16 * 32B = 512B coalesced per row
        v4f* op = (v4f*)(out + ((size_t)row << 7) + t * 8);
        v4f o0; o0.x = a0; o0.y = a1; o0.z = a2; o0.w = a3;
        v4f o1; o1.x = a4; o1.y = a5; o1.z = a6; o1.w = a7;
        __builtin_nontemporal_store(o0, op);
        __builtin_nontemporal_store(o1, op + 1);
    }
}

// ===================== fallback (tiny ws; never expected) ===================
__global__ void fallback_kernel(const float* __restrict__ x,
                                const int* __restrict__ rows,
                                const int* __restrict__ cols,
                                const float* __restrict__ vals,
                                float* __restrict__ out, int n_edges) {
    int gid = blockIdx.x * blockDim.x + threadIdx.x;
    int e = gid >> 5, t = gid & 31;
    if (e >= n_edges) return;
    int c = cols[e];
    const float* xr = x + (size_t)c * D_FEAT;
    float ss = 0.0f;
    for (int i = 0; i < D_FEAT; ++i) ss += xr[i] * xr[i];
    float nc = fmaxf(sqrtf(ss), 1e-15f);
    float u = fminf(nc, 1.0f - 1e-15f);
    float w = vals[e] * (0.5f * (log1pf(u) - log1pf(-u))) / nc;
    const float4* xc = (const float4*)xr;
    float4 xv = xc[t];
    float* o = out + (size_t)rows[e] * D_FEAT + t * 4;
    atomicAdd(o + 0, w * xv.x);
    atomicAdd(o + 1, w * xv.y);
    atomicAdd(o + 2, w * xv.z);
    atomicAdd(o + 3, w * xv.w);
}

// ============================================================================

extern "C" void kernel_launch(void* const* d_in, const int* in_sizes, int n_in,
                              void* d_out, int out_size, void* d_ws, size_t ws_size,
                              hipStream_t stream) {
    const float* x    = (const float*)d_in[0];
    const int*   rows = (const int*)d_in[1];
    const int*   cols = (const int*)d_in[2];
    const float* vals = (const float*)d_in[3];
    float* out = (float*)d_out;

    const int n_nodes = in_sizes[0] / D_FEAT;  // 50000
    const int n_edges = in_sizes[1];           // 800000

    char* wsb = (char*)d_ws;
    const int n_scatter_blocks = (n_edges + P1_EPB - 1) / P1_EPB;  // 125
    const int n_scale_blocks   = (n_nodes + 3) / 4;                // 12500

    size_t xt_bytes    = (size_t)n_nodes * D_FEAT * 2;             // 12.8 MB
    size_t gcur_off    = xt_bytes;
    size_t ocount_off  = gcur_off + (size_t)NBINS * 4;
    size_t oedges_off  = (ocount_off + 4 + 255) & ~(size_t)255;
    size_t binned_off  = (oedges_off + (size_t)OCAP * 16 + 511) & ~(size_t)511;
    size_t need        = binned_off + (size_t)NBINS * CAPB * 8;    // ~21.3 MB

    if (ws_size >= need) {
        unsigned short* xt = (unsigned short*)wsb;
        int*  gcur    = (int*)(wsb + gcur_off);
        int*  ocount  = (int*)(wsb + ocount_off);
        int4* oedges  = (int4*)(wsb + oedges_off);
        int*  binned  = (int*)(wsb + binned_off);

        // zero bin cursors + ocount in one memset
        hipMemsetAsync(gcur, 0, ocount_off + 4 - gcur_off, stream);
        bin_scale_kernel<<<n_scatter_blocks + n_scale_blocks, 256, 0, stream>>>(
            x, xt, rows, cols, vals, gcur, binned, ocount, oedges,
            n_nodes, n_edges, n_scatter_blocks);
        gather_binned_kernel<<<NBINS, 256, 0, stream>>>(
            xt, gcur, binned, ocount, oedges, out, n_nodes);
    } else {
        hipMemsetAsync(out, 0, (size_t)out_size * sizeof(float), stream);
        long long total = (long long)n_edges * 32;
        fallback_kernel<<<(int)((total + 255) / 256), 256, 0, stream>>>(
            x, rows, cols, vals, out, n_edges);
    }
}

// Round 5
// 139.825 us; speedup vs baseline: 1.1282x; 1.0036x over previous
//
#include <hip/hip_runtime.h>
#include <math.h>

#define D_FEAT 128
#define NBINS 1024          // bin = row & 1023; bin rows are row = bin + l*1024, l<49
#define BIN_MASK (NBINS - 1)
#define CAPB 1024           // slots per bin (avg 781, +8.7 sigma) -> overflow list
#define OCAP 4096
#define P1_EPB 6400         // edges per phase-1 scatter block (25/thread)

typedef float    v2f __attribute__((ext_vector_type(2)));
typedef int      v2i __attribute__((ext_vector_type(2)));
typedef unsigned v2u __attribute__((ext_vector_type(2)));
typedef float    v4f __attribute__((ext_vector_type(4)));
typedef int      v4i __attribute__((ext_vector_type(4)));
typedef unsigned v4u __attribute__((ext_vector_type(4)));

static __device__ inline unsigned short f2bf(float f) {
    unsigned u = __float_as_uint(f);
    u += 0x7FFFu + ((u >> 16) & 1u);   // round-to-nearest-even
    return (unsigned short)(u >> 16);
}

// ===================== phase 1: fused binning + scale =======================
// Scatter role (blocks [0, nsb)): two-pass LDS binning, edge loads batched
// 4-wide (ext-vector NT loads). Reserve: one global atomic per (block,bin).
// Scale role: 2 rows per wave, v4f (16B/lane) NT loads, 32-lane norm reduce,
// 8B packed bf16 NT stores — halves wave count vs 1-row/wave.
__global__ void __launch_bounds__(256)
bin_scale_kernel(const float* __restrict__ x,
                 unsigned short* __restrict__ xt,
                 const int* __restrict__ rows,
                 const int* __restrict__ cols,
                 const float* __restrict__ vals,
                 int* __restrict__ gcur,      // NBINS ints (zeroed)
                 int* __restrict__ binned,    // v2i entries, bin*CAPB
                 int* __restrict__ ocount,
                 int4* __restrict__ oedges,
                 int n_nodes, int n_edges, int n_scatter_blocks) {
    __shared__ int cnt1[NBINS];
    __shared__ int base1[NBINS];
    __shared__ int runc[NBINS];
    if ((int)blockIdx.x < n_scatter_blocks) {
        const int tid = threadIdx.x;
        for (int b = tid; b < NBINS; b += 256) { cnt1[b] = 0; runc[b] = 0; }
        __syncthreads();
        const int e0 = blockIdx.x * P1_EPB;
        const int e1 = min(e0 + P1_EPB, n_edges);
        const int nfull = (e1 - e0) & ~3;      // 4-aligned prefix
        // pass A: count (4 edges per v4i load, pipelined)
        for (int e = e0 + (tid << 2); e + 3 < e1; e += 1024) {
            v4i r4 = __builtin_nontemporal_load((const v4i*)(rows + e));
            atomicAdd(&cnt1[r4[0] & BIN_MASK], 1);
            atomicAdd(&cnt1[r4[1] & BIN_MASK], 1);
            atomicAdd(&cnt1[r4[2] & BIN_MASK], 1);
            atomicAdd(&cnt1[r4[3] & BIN_MASK], 1);
        }
        for (int e = e0 + nfull + tid; e < e1; e += 256) {   // ragged tail
            int r = __builtin_nontemporal_load(rows + e);
            atomicAdd(&cnt1[r & BIN_MASK], 1);
        }
        __syncthreads();
        // reserve: one global atomic per nonempty (block,bin)
        for (int b = tid; b < NBINS; b += 256) {
            int c = cnt1[b];
            base1[b] = c ? atomicAdd(&gcur[b], c) : 0;
        }
        __syncthreads();
        // pass B: grouped writes (4 edges per iteration, 3 vector loads)
        for (int e = e0 + (tid << 2); e + 3 < e1; e += 1024) {
            v4i r4 = __builtin_nontemporal_load((const v4i*)(rows + e));
            v4i c4 = __builtin_nontemporal_load((const v4i*)(cols + e));
            v4f v4 = __builtin_nontemporal_load((const v4f*)(vals + e));
            #pragma unroll
            for (int k = 0; k < 4; ++k) {
                int   r = r4[k];
                int   c = c4[k];
                float v = v4[k];
                int b = r & BIN_MASK;
                int slot = atomicAdd(&runc[b], 1);     // LDS
                int idx = base1[b] + slot;
                if (idx < CAPB) {
                    v2i p;
                    p.x = c | ((r >> 10) << 16);       // col<65536, local<64
                    p.y = __float_as_int(v);
                    *((v2i*)(binned + 2 * ((size_t)b * CAPB + idx))) = p;
                } else {  // astronomically rare
                    int o = atomicAdd(ocount, 1);
                    if (o < OCAP) {
                        int4 q; q.x = r; q.y = c; q.z = __float_as_int(v); q.w = 0;
                        oedges[o] = q;
                    }
                }
            }
        }
        for (int e = e0 + nfull + tid; e < e1; e += 256) {   // ragged tail
            int   r = __builtin_nontemporal_load(rows + e);
            int   c = __builtin_nontemporal_load(cols + e);
            float v = __builtin_nontemporal_load(vals + e);
            int b = r & BIN_MASK;
            int slot = atomicAdd(&runc[b], 1);
            int idx = base1[b] + slot;
            if (idx < CAPB) {
                v2i p;
                p.x = c | ((r >> 10) << 16);
                p.y = __float_as_int(v);
                *((v2i*)(binned + 2 * ((size_t)b * CAPB + idx))) = p;
            } else {
                int o = atomicAdd(ocount, 1);
                if (o < OCAP) {
                    int4 q; q.x = r; q.y = c; q.z = __float_as_int(v); q.w = 0;
                    oedges[o] = q;
                }
            }
        }
    } else {
        // scale role: 2 rows per wave (lanes 0-31 -> row even, 32-63 -> odd)
        const int lane = threadIdx.x & 63;
        const int wave = threadIdx.x >> 6;
        const int half = lane >> 5;
        const int sub  = lane & 31;
        const int row = (((int)blockIdx.x - n_scatter_blocks) * 4 + wave) * 2 + half;
        if (row >= n_nodes) return;

        v4f v = __builtin_nontemporal_load(
            (const v4f*)(x + (size_t)row * D_FEAT) + sub);
        float ss = v.x * v.x + v.y * v.y + v.z * v.z + v.w * v.w;
        // reduce over 32 lanes (xor masks < 32 stay within the half)
        #pragma unroll
        for (int off = 16; off > 0; off >>= 1)
            ss += __shfl_xor(ss, off, 64);

        float norm = sqrtf(ss);
        float nc = fmaxf(norm, 1e-15f);
        float u = fminf(nc, 1.0f - 1e-15f);
        float at = 0.5f * (log1pf(u) - log1pf(-u));
        float s = at / nc;

        v2u pk;
        pk.x = (unsigned)f2bf(v.x * s) | ((unsigned)f2bf(v.y * s) << 16);
        pk.y = (unsigned)f2bf(v.z * s) | ((unsigned)f2bf(v.w * s) << 16);
        __builtin_nontemporal_store(
            pk, (v2u*)(xt + (size_t)row * D_FEAT) + sub);
    }
}

// ===================== phase 2: per-bin counting-sort + gather ==============
// One block of 256 threads per bin; __launch_bounds__(256,4) -> VGPR<=128.
// 16 groups of 16 lanes, each group exclusively owns rows l = grp, grp+16,...
// Inner loop UNROLL-8: 8 independent 16B xt loads in flight per group (the
// kernel is latency-bound on these random LLC-class fetches; R4's unroll-4
// left MLP at half of what the register budget allows). sorted[] zero-padded
// 8 deep so only weights need masking, never addresses; padded slots read
// xt row 0 (L2-hot).
__global__ void __launch_bounds__(256, 4)
gather_binned_kernel(const unsigned short* __restrict__ xt,
                     const int* __restrict__ gcur,
                     const int* __restrict__ binned,
                     const int* __restrict__ ocount,
                     const int4* __restrict__ oedges,
                     float* __restrict__ out, int n_nodes) {
    __shared__ v2i elist[CAPB];        // 8 KB
    __shared__ v2i sorted[CAPB + 8];   // 8 KB + pad
    __shared__ int rcnt[64], roff[64], rcur[64];

    const int bin = blockIdx.x;
    const int tid = threadIdx.x;
    const int total = gcur[bin];
    const bool over = total > CAPB;
    const int cnt = over ? CAPB : total;

    if (tid < 64) { rcnt[tid] = 0; rcur[tid] = 0; }
    __syncthreads();

    // load + count by local row
    for (int i = tid; i < cnt; i += 256) {
        v2i w = ((const v2i*)(binned + 2 * (size_t)bin * CAPB))[i];
        elist[i] = w;
        atomicAdd(&rcnt[(w.x >> 16) & 63], 1);
    }
    __syncthreads();
    // exclusive scan (49 rows) by wave 0
    if (tid < 64) {
        int v = rcnt[tid];
        int s = v;
        #pragma unroll
        for (int off = 1; off < 64; off <<= 1) {
            int t = __shfl_up(s, off, 64);
            if (tid >= (unsigned)off) s += t;
        }
        roff[tid] = s - v;
    }
    __syncthreads();
    // scatter into row-sorted order
    for (int i = tid; i < cnt; i += 256) {
        v2i w = elist[i];
        int l = (w.x >> 16) & 63;
        int slot = atomicAdd(&rcur[l], 1);
        sorted[roff[l] + slot] = w;
    }
    // zero-pad tail so unroll-8 reads past the last row are {col=0, w=0}
    if (tid < 8) { v2i z; z.x = 0; z.y = 0; sorted[cnt + tid] = z; }
    __syncthreads();

    const int grp = tid >> 4;        // 0..15: group-per-row
    const int t   = tid & 15;        // feature lane within group
    const int nrows = (n_nodes - bin + NBINS - 1) >> 10;   // 48 or 49

    for (int l = grp; l < nrows; l += 16) {
        const int row = bin + (l << 10);
        const int deg = rcnt[l];
        const int off = roff[l];

        float a0 = 0, a1 = 0, a2 = 0, a3 = 0, a4 = 0, a5 = 0, a6 = 0, a7 = 0;

        for (int j = 0; j < deg; j += 8) {
            // 8 unconditional LDS reads (pad/next-row entries are safe cols)
            v2i e[8];
            #pragma unroll
            for (int k = 0; k < 8; ++k) e[k] = sorted[off + j + k];
            // 8 independent 16B loads in flight
            float w[8];
            v4u u[8];
            #pragma unroll
            for (int k = 0; k < 8; ++k) {
                w[k] = (j + k < deg) ? __int_as_float(e[k].y) : 0.0f;
                u[k] = ((const v4u*)(xt + ((size_t)(e[k].x & 0xFFFF) << 7)))[t];
            }
            #pragma unroll
            for (int k = 0; k < 8; ++k) {
                a0 = fmaf(w[k], __uint_as_float(u[k].x << 16), a0);
                a1 = fmaf(w[k], __uint_as_float(u[k].x & 0xFFFF0000u), a1);
                a2 = fmaf(w[k], __uint_as_float(u[k].y << 16), a2);
                a3 = fmaf(w[k], __uint_as_float(u[k].y & 0xFFFF0000u), a3);
                a4 = fmaf(w[k], __uint_as_float(u[k].z << 16), a4);
                a5 = fmaf(w[k], __uint_as_float(u[k].z & 0xFFFF0000u), a5);
                a6 = fmaf(w[k], __uint_as_float(u[k].w << 16), a6);
                a7 = fmaf(w[k], __uint_as_float(u[k].w & 0xFFFF0000u), a7);
            }
        }

        if (over) {  // exact rescue of edges that missed the bin region
            int n = *ocount;
            n = n < OCAP ? n : OCAP;
            for (int j = 0; j < n; ++j) {
                int4 q = oedges[j];
                if (q.x == row) {   // group owns this row exclusively
                    float w = __int_as_float(q.z);
                    v4u u = ((const v4u*)(xt + ((size_t)q.y << 7)))[t];
                    a0 = fmaf(w, __uint_as_float(u.x << 16), a0);
                    a1 = fmaf(w, __uint_as_float(u.x & 0xFFFF0000u), a1);
                    a2 = fmaf(w, __uint_as_float(u.y << 16), a2);
                    a3 = fmaf(w, __uint_as_float(u.y & 0xFFFF0000u), a3);
                    a4 = fmaf(w, __uint_as_float(u.z << 16), a4);
                    a5 = fmaf(w, __uint_as_float(u.z & 0xFFFF0000u), a5);
                    a6 = fmaf(w, __uint_as_float(u.w << 16), a6);
                    a7 = fmaf(w, __uint_as_float(u.w & 0xFFFF0000u), a7);
                }
            }
        }

        // all 16 lanes store: 16 * 32B = 512B coalesced per row
        v4f* op = (v4f*)(out + ((size_t)row << 7) + t * 8);
        v4f o0; o0.x = a0; o0.y = a1; o0.z = a2; o0.w = a3;
        v4f o1; o1.x = a4; o1.y = a5; o1.z = a6; o1.w = a7;
        __builtin_nontemporal_store(o0, op);
        __builtin_nontemporal_store(o1, op + 1);
    }
}

// ===================== fallback (tiny ws; never expected) ===================
__global__ void fallback_kernel(const float* __restrict__ x,
                                const int* __restrict__ rows,
                                const int* __restrict__ cols,
                                const float* __restrict__ vals,
                                float* __restrict__ out, int n_edges) {
    int gid = blockIdx.x * blockDim.x + threadIdx.x;
    int e = gid >> 5, t = gid & 31;
    if (e >= n_edges) return;
    int c = cols[e];
    const float* xr = x + (size_t)c * D_FEAT;
    float ss = 0.0f;
    for (int i = 0; i < D_FEAT; ++i) ss += xr[i] * xr[i];
    float nc = fmaxf(sqrtf(ss), 1e-15f);
    float u = fminf(nc, 1.0f - 1e-15f);
    float w = vals[e] * (0.5f * (log1pf(u) - log1pf(-u))) / nc;
    const float4* xc = (const float4*)xr;
    float4 xv = xc[t];
    float* o = out + (size_t)rows[e] * D_FEAT + t * 4;
    atomicAdd(o + 0, w * xv.x);
    atomicAdd(o + 1, w * xv.y);
    atomicAdd(o + 2, w * xv.z);
    atomicAdd(o + 3, w * xv.w);
}

// ============================================================================

extern "C" void kernel_launch(void* const* d_in, const int* in_sizes, int n_in,
                              void* d_out, int out_size, void* d_ws, size_t ws_size,
                              hipStream_t stream) {
    const float* x    = (const float*)d_in[0];
    const int*   rows = (const int*)d_in[1];
    const int*   cols = (const int*)d_in[2];
    const float* vals = (const float*)d_in[3];
    float* out = (float*)d_out;

    const int n_nodes = in_sizes[0] / D_FEAT;  // 50000
    const int n_edges = in_sizes[1];           // 800000

    char* wsb = (char*)d_ws;
    const int n_scatter_blocks = (n_edges + P1_EPB - 1) / P1_EPB;  // 125
    const int n_scale_blocks   = (n_nodes + 7) / 8;                // 6250 (2 rows/wave)

    size_t xt_bytes    = (size_t)n_nodes * D_FEAT * 2;             // 12.8 MB
    size_t gcur_off    = xt_bytes;
    size_t ocount_off  = gcur_off + (size_t)NBINS * 4;
    size_t oedges_off  = (ocount_off + 4 + 255) & ~(size_t)255;
    size_t binned_off  = (oedges_off + (size_t)OCAP * 16 + 511) & ~(size_t)511;
    size_t need        = binned_off + (size_t)NBINS * CAPB * 8;    // ~21.3 MB

    if (ws_size >= need) {
        unsigned short* xt = (unsigned short*)wsb;
        int*  gcur    = (int*)(wsb + gcur_off);
        int*  ocount  = (int*)(wsb + ocount_off);
        int4* oedges  = (int4*)(wsb + oedges_off);
        int*  binned  = (int*)(wsb + binned_off);

        // zero bin cursors + ocount in one memset
        hipMemsetAsync(gcur, 0, ocount_off + 4 - gcur_off, stream);
        bin_scale_kernel<<<n_scatter_blocks + n_scale_blocks, 256, 0, stream>>>(
            x, xt, rows, cols, vals, gcur, binned, ocount, oedges,
            n_nodes, n_edges, n_scatter_blocks);
        gather_binned_kernel<<<NBINS, 256, 0, stream>>>(
            xt, gcur, binned, ocount, oedges, out, n_nodes);
    } else {
        hipMemsetAsync(out, 0, (size_t)out_size * sizeof(float), stream);
        long long total = (long long)n_edges * 32;
        fallback_kernel<<<(int)((total + 255) / 256), 256, 0, stream>>>(
            x, rows, cols, vals, out, n_edges);
    }
}

// Round 6
// 139.625 us; speedup vs baseline: 1.1298x; 1.0014x over previous
//
#include <hip/hip_runtime.h>
#include <math.h>

#define D_FEAT 128
#define NBINS 1024          // bin = row & 1023; bin rows are row = bin + l*1024, l<49
#define BIN_MASK (NBINS - 1)
#define CAPB 1024           // slots per bin (avg 781, +8.7 sigma) -> overflow list
#define OCAP 4096
#define P1_EPB 6400         // edges per phase-1 scatter block (25/thread)

typedef float    v2f __attribute__((ext_vector_type(2)));
typedef int      v2i __attribute__((ext_vector_type(2)));
typedef unsigned v2u __attribute__((ext_vector_type(2)));
typedef float    v4f __attribute__((ext_vector_type(4)));
typedef int      v4i __attribute__((ext_vector_type(4)));
typedef unsigned v4u __attribute__((ext_vector_type(4)));

static __device__ inline unsigned short f2bf(float f) {
    unsigned u = __float_as_uint(f);
    u += 0x7FFFu + ((u >> 16) & 1u);   // round-to-nearest-even
    return (unsigned short)(u >> 16);
}

// ===================== phase 1: fused binning + scale =======================
// Scatter role (blocks [0, nsb)): two-pass LDS binning, edge loads batched
// 4-wide (ext-vector NT loads). Reserve: one global atomic per (block,bin).
// Scale role: 2 rows per wave, v4f (16B/lane) NT loads, 32-lane norm reduce,
// 8B packed bf16 stores. xt store is CACHED (not NT): gather re-reads every
// xt line ~16x — NT no-allocate hint pushed gather's first touches to HBM.
__global__ void __launch_bounds__(256)
bin_scale_kernel(const float* __restrict__ x,
                 unsigned short* __restrict__ xt,
                 const int* __restrict__ rows,
                 const int* __restrict__ cols,
                 const float* __restrict__ vals,
                 int* __restrict__ gcur,      // NBINS ints (zeroed)
                 int* __restrict__ binned,    // v2i entries, bin*CAPB
                 int* __restrict__ ocount,
                 int4* __restrict__ oedges,
                 int n_nodes, int n_edges, int n_scatter_blocks) {
    __shared__ int cnt1[NBINS];
    __shared__ int base1[NBINS];
    __shared__ int runc[NBINS];
    if ((int)blockIdx.x < n_scatter_blocks) {
        const int tid = threadIdx.x;
        for (int b = tid; b < NBINS; b += 256) { cnt1[b] = 0; runc[b] = 0; }
        __syncthreads();
        const int e0 = blockIdx.x * P1_EPB;
        const int e1 = min(e0 + P1_EPB, n_edges);
        const int nfull = (e1 - e0) & ~3;      // 4-aligned prefix
        // pass A: count (4 edges per v4i load, pipelined)
        for (int e = e0 + (tid << 2); e + 3 < e1; e += 1024) {
            v4i r4 = __builtin_nontemporal_load((const v4i*)(rows + e));
            atomicAdd(&cnt1[r4[0] & BIN_MASK], 1);
            atomicAdd(&cnt1[r4[1] & BIN_MASK], 1);
            atomicAdd(&cnt1[r4[2] & BIN_MASK], 1);
            atomicAdd(&cnt1[r4[3] & BIN_MASK], 1);
        }
        for (int e = e0 + nfull + tid; e < e1; e += 256) {   // ragged tail
            int r = __builtin_nontemporal_load(rows + e);
            atomicAdd(&cnt1[r & BIN_MASK], 1);
        }
        __syncthreads();
        // reserve: one global atomic per nonempty (block,bin)
        for (int b = tid; b < NBINS; b += 256) {
            int c = cnt1[b];
            base1[b] = c ? atomicAdd(&gcur[b], c) : 0;
        }
        __syncthreads();
        // pass B: grouped writes (4 edges per iteration, 3 vector loads)
        for (int e = e0 + (tid << 2); e + 3 < e1; e += 1024) {
            v4i r4 = __builtin_nontemporal_load((const v4i*)(rows + e));
            v4i c4 = __builtin_nontemporal_load((const v4i*)(cols + e));
            v4f v4 = __builtin_nontemporal_load((const v4f*)(vals + e));
            #pragma unroll
            for (int k = 0; k < 4; ++k) {
                int   r = r4[k];
                int   c = c4[k];
                float v = v4[k];
                int b = r & BIN_MASK;
                int slot = atomicAdd(&runc[b], 1);     // LDS
                int idx = base1[b] + slot;
                if (idx < CAPB) {
                    v2i p;
                    p.x = c | ((r >> 10) << 16);       // col<65536, local<64
                    p.y = __float_as_int(v);
                    *((v2i*)(binned + 2 * ((size_t)b * CAPB + idx))) = p;
                } else {  // astronomically rare
                    int o = atomicAdd(ocount, 1);
                    if (o < OCAP) {
                        int4 q; q.x = r; q.y = c; q.z = __float_as_int(v); q.w = 0;
                        oedges[o] = q;
                    }
                }
            }
        }
        for (int e = e0 + nfull + tid; e < e1; e += 256) {   // ragged tail
            int   r = __builtin_nontemporal_load(rows + e);
            int   c = __builtin_nontemporal_load(cols + e);
            float v = __builtin_nontemporal_load(vals + e);
            int b = r & BIN_MASK;
            int slot = atomicAdd(&runc[b], 1);
            int idx = base1[b] + slot;
            if (idx < CAPB) {
                v2i p;
                p.x = c | ((r >> 10) << 16);
                p.y = __float_as_int(v);
                *((v2i*)(binned + 2 * ((size_t)b * CAPB + idx))) = p;
            } else {
                int o = atomicAdd(ocount, 1);
                if (o < OCAP) {
                    int4 q; q.x = r; q.y = c; q.z = __float_as_int(v); q.w = 0;
                    oedges[o] = q;
                }
            }
        }
    } else {
        // scale role: 2 rows per wave (lanes 0-31 -> row even, 32-63 -> odd)
        const int lane = threadIdx.x & 63;
        const int wave = threadIdx.x >> 6;
        const int half = lane >> 5;
        const int sub  = lane & 31;
        const int row = (((int)blockIdx.x - n_scatter_blocks) * 4 + wave) * 2 + half;
        if (row >= n_nodes) return;

        v4f v = __builtin_nontemporal_load(
            (const v4f*)(x + (size_t)row * D_FEAT) + sub);
        float ss = v.x * v.x + v.y * v.y + v.z * v.z + v.w * v.w;
        // reduce over 32 lanes (xor masks < 32 stay within the half)
        #pragma unroll
        for (int off = 16; off > 0; off >>= 1)
            ss += __shfl_xor(ss, off, 64);

        float norm = sqrtf(ss);
        float nc = fmaxf(norm, 1e-15f);
        float u = fminf(nc, 1.0f - 1e-15f);
        float at = 0.5f * (log1pf(u) - log1pf(-u));
        float s = at / nc;

        v2u pk;
        pk.x = (unsigned)f2bf(v.x * s) | ((unsigned)f2bf(v.y * s) << 16);
        pk.y = (unsigned)f2bf(v.z * s) | ((unsigned)f2bf(v.w * s) << 16);
        // cached store (gather re-reads xt ~16x; let it allocate in LLC)
        *((v2u*)(xt + (size_t)row * D_FEAT) + sub) = pk;
    }
}

// ===================== phase 2: per-bin counting-sort + gather ==============
// One block of 256 threads per bin; __launch_bounds__(256,6) -> VGPR<=80,
// 6 blocks/CU (24 waves/CU): the R4/R5 4-blocks/CU version serialized each
// block's ~2us sort preamble per CU and ran at 50% occupancy. Unroll-4
// (R5 proved unroll-8 == unroll-4, and 4 fits the 80-VGPR budget without
// spill). 16 groups of 16 lanes, group-per-row, all-lane coalesced stores.
__global__ void __launch_bounds__(256, 6)
gather_binned_kernel(const unsigned short* __restrict__ xt,
                     const int* __restrict__ gcur,
                     const int* __restrict__ binned,
                     const int* __restrict__ ocount,
                     const int4* __restrict__ oedges,
                     float* __restrict__ out, int n_nodes) {
    __shared__ v2i elist[CAPB];        // 8 KB
    __shared__ v2i sorted[CAPB + 4];   // 8 KB + pad
    __shared__ int rcnt[64], roff[64], rcur[64];

    const int bin = blockIdx.x;
    const int tid = threadIdx.x;
    const int total = gcur[bin];
    const bool over = total > CAPB;
    const int cnt = over ? CAPB : total;

    if (tid < 64) { rcnt[tid] = 0; rcur[tid] = 0; }
    __syncthreads();

    // load + count by local row
    for (int i = tid; i < cnt; i += 256) {
        v2i w = ((const v2i*)(binned + 2 * (size_t)bin * CAPB))[i];
        elist[i] = w;
        atomicAdd(&rcnt[(w.x >> 16) & 63], 1);
    }
    __syncthreads();
    // exclusive scan (49 rows) by wave 0
    if (tid < 64) {
        int v = rcnt[tid];
        int s = v;
        #pragma unroll
        for (int off = 1; off < 64; off <<= 1) {
            int t = __shfl_up(s, off, 64);
            if (tid >= (unsigned)off) s += t;
        }
        roff[tid] = s - v;
    }
    __syncthreads();
    // scatter into row-sorted order
    for (int i = tid; i < cnt; i += 256) {
        v2i w = elist[i];
        int l = (w.x >> 16) & 63;
        int slot = atomicAdd(&rcur[l], 1);
        sorted[roff[l] + slot] = w;
    }
    // zero-pad tail so unroll-4 reads past the last row are {col=0, w=0}
    if (tid < 4) { v2i z; z.x = 0; z.y = 0; sorted[cnt + tid] = z; }
    __syncthreads();

    const int grp = tid >> 4;        // 0..15: group-per-row
    const int t   = tid & 15;        // feature lane within group
    const int nrows = (n_nodes - bin + NBINS - 1) >> 10;   // 48 or 49

    for (int l = grp; l < nrows; l += 16) {
        const int row = bin + (l << 10);
        const int deg = rcnt[l];
        const int off = roff[l];

        float a0 = 0, a1 = 0, a2 = 0, a3 = 0, a4 = 0, a5 = 0, a6 = 0, a7 = 0;

        for (int j = 0; j < deg; j += 4) {
            // 4 unconditional LDS reads (pad/next-row entries are safe cols)
            v2i e[4];
            #pragma unroll
            for (int k = 0; k < 4; ++k) e[k] = sorted[off + j + k];
            float w[4];
            v4u u[4];
            #pragma unroll
            for (int k = 0; k < 4; ++k) {
                w[k] = (j + k < deg) ? __int_as_float(e[k].y) : 0.0f;
                u[k] = ((const v4u*)(xt + ((size_t)(e[k].x & 0xFFFF) << 7)))[t];
            }
            #pragma unroll
            for (int k = 0; k < 4; ++k) {
                a0 = fmaf(w[k], __uint_as_float(u[k].x << 16), a0);
                a1 = fmaf(w[k], __uint_as_float(u[k].x & 0xFFFF0000u), a1);
                a2 = fmaf(w[k], __uint_as_float(u[k].y << 16), a2);
                a3 = fmaf(w[k], __uint_as_float(u[k].y & 0xFFFF0000u), a3);
                a4 = fmaf(w[k], __uint_as_float(u[k].z << 16), a4);
                a5 = fmaf(w[k], __uint_as_float(u[k].z & 0xFFFF0000u), a5);
                a6 = fmaf(w[k], __uint_as_float(u[k].w << 16), a6);
                a7 = fmaf(w[k], __uint_as_float(u[k].w & 0xFFFF0000u), a7);
            }
        }

        if (over) {  // exact rescue of edges that missed the bin region
            int n = *ocount;
            n = n < OCAP ? n : OCAP;
            for (int j = 0; j < n; ++j) {
                int4 q = oedges[j];
                if (q.x == row) {   // group owns this row exclusively
                    float w = __int_as_float(q.z);
                    v4u u = ((const v4u*)(xt + ((size_t)q.y << 7)))[t];
                    a0 = fmaf(w, __uint_as_float(u.x << 16), a0);
                    a1 = fmaf(w, __uint_as_float(u.x & 0xFFFF0000u), a1);
                    a2 = fmaf(w, __uint_as_float(u.y << 16), a2);
                    a3 = fmaf(w, __uint_as_float(u.y & 0xFFFF0000u), a3);
                    a4 = fmaf(w, __uint_as_float(u.z << 16), a4);
                    a5 = fmaf(w, __uint_as_float(u.z & 0xFFFF0000u), a5);
                    a6 = fmaf(w, __uint_as_float(u.w << 16), a6);
                    a7 = fmaf(w, __uint_as_float(u.w & 0xFFFF0000u), a7);
                }
            }
        }

        // all 16 lanes store: 16 * 32B = 512B coalesced per row
        v4f* op = (v4f*)(out + ((size_t)row << 7) + t * 8);
        v4f o0; o0.x = a0; o0.y = a1; o0.z = a2; o0.w = a3;
        v4f o1; o1.x = a4; o1.y = a5; o1.z = a6; o1.w = a7;
        __builtin_nontemporal_store(o0, op);
        __builtin_nontemporal_store(o1, op + 1);
    }
}

// ===================== fallback (tiny ws; never expected) ===================
__global__ void fallback_kernel(const float* __restrict__ x,
                                const int* __restrict__ rows,
                                const int* __restrict__ cols,
                                const float* __restrict__ vals,
                                float* __restrict__ out, int n_edges) {
    int gid = blockIdx.x * blockDim.x + threadIdx.x;
    int e = gid >> 5, t = gid & 31;
    if (e >= n_edges) return;
    int c = cols[e];
    const float* xr = x + (size_t)c * D_FEAT;
    float ss = 0.0f;
    for (int i = 0; i < D_FEAT; ++i) ss += xr[i] * xr[i];
    float nc = fmaxf(sqrtf(ss), 1e-15f);
    float u = fminf(nc, 1.0f - 1e-15f);
    float w = vals[e] * (0.5f * (log1pf(u) - log1pf(-u))) / nc;
    const float4* xc = (const float4*)xr;
    float4 xv = xc[t];
    float* o = out + (size_t)rows[e] * D_FEAT + t * 4;
    atomicAdd(o + 0, w * xv.x);
    atomicAdd(o + 1, w * xv.y);
    atomicAdd(o + 2, w * xv.z);
    atomicAdd(o + 3, w * xv.w);
}

// ============================================================================

extern "C" void kernel_launch(void* const* d_in, const int* in_sizes, int n_in,
                              void* d_out, int out_size, void* d_ws, size_t ws_size,
                              hipStream_t stream) {
    const float* x    = (const float*)d_in[0];
    const int*   rows = (const int*)d_in[1];
    const int*   cols = (const int*)d_in[2];
    const float* vals = (const float*)d_in[3];
    float* out = (float*)d_out;

    const int n_nodes = in_sizes[0] / D_FEAT;  // 50000
    const int n_edges = in_sizes[1];           // 800000

    char* wsb = (char*)d_ws;
    const int n_scatter_blocks = (n_edges + P1_EPB - 1) / P1_EPB;  // 125
    const int n_scale_blocks   = (n_nodes + 7) / 8;                // 6250 (2 rows/wave)

    size_t xt_bytes    = (size_t)n_nodes * D_FEAT * 2;             // 12.8 MB
    size_t gcur_off    = xt_bytes;
    size_t ocount_off  = gcur_off + (size_t)NBINS * 4;
    size_t oedges_off  = (ocount_off + 4 + 255) & ~(size_t)255;
    size_t binned_off  = (oedges_off + (size_t)OCAP * 16 + 511) & ~(size_t)511;
    size_t need        = binned_off + (size_t)NBINS * CAPB * 8;    // ~21.3 MB

    if (ws_size >= need) {
        unsigned short* xt = (unsigned short*)wsb;
        int*  gcur    = (int*)(wsb + gcur_off);
        int*  ocount  = (int*)(wsb + ocount_off);
        int4* oedges  = (int4*)(wsb + oedges_off);
        int*  binned  = (int*)(wsb + binned_off);

        // zero bin cursors + ocount in one memset
        hipMemsetAsync(gcur, 0, ocount_off + 4 - gcur_off, stream);
        bin_scale_kernel<<<n_scatter_blocks + n_scale_blocks, 256, 0, stream>>>(
            x, xt, rows, cols, vals, gcur, binned, ocount, oedges,
            n_nodes, n_edges, n_scatter_blocks);
        gather_binned_kernel<<<NBINS, 256, 0, stream>>>(
            xt, gcur, binned, ocount, oedges, out, n_nodes);
    } else {
        hipMemsetAsync(out, 0, (size_t)out_size * sizeof(float), stream);
        long long total = (long long)n_edges * 32;
        fallback_kernel<<<(int)((total + 255) / 256), 256, 0, stream>>>(
            x, rows, cols, vals, out, n_edges);
    }
}